// Round 8
// baseline (66.539 us; speedup 1.0000x reference)
//
#include <hip/hip_runtime.h>
#include <hip/hip_bf16.h>
#include <math.h>

// DiscriminationLoss via MFMA (R8):
//   S[k,c] = sum_{p: label[p]=k} pred[c,p],  N[k] = |{p: label[p]=k}|, k=1..32
//   A[k]   = N[k] * sum_c S[k,c]^2
//   L      = sum_{i<j} log(max(3 - sqrt(A_i + A_j), 0)^2 + 1);  out = L*(K-1)/K
//
// R7 lesson: the LDS round-trip (27 ds-ops/tile ~ 17us/CU of LDS-pipe time +
// write->lgkm->read serialization) was the floor; 2-deep prefetch didn't move
// the total. R8 removes LDS entirely:
//   - labels: broadcast int4 global loads (4 distinct addrs/wave, L1-hit)
//   - pred:   per-lane float4 global loads (each byte fetched once)
//   - 2x mfma_f32_16x16x32_bf16 (segs 1..16 and 17..32 share one B operand)
//   - 4-deep named-register k-step pipeline, contiguous per-wave px chunks
//   - zero atomics / zero memset anywhere: plain-store slab partials,
//     level-1 reduce (32 blocks), finish sums 32x288.

typedef __attribute__((ext_vector_type(8))) short short8;
typedef __attribute__((ext_vector_type(4))) float f32x4;

constexpr int NSEGF = 32;            // segments 1..32 (label 0 = background, dropped)
constexpr int RPS   = 9;             // 8 channels + count
constexpr int NROWS = NSEGF * RPS;   // 288
constexpr int BLK   = 256;
constexpr int WPB   = 4;
constexpr int NBLK  = 2048;
constexpr int NWAVE = NBLK * WPB;    // 8192 waves
constexpr int PXS   = 32;            // pixels per k-step (K of 16x16x32)
constexpr int L1BLK = 32;            // level-1 reduce blocks
constexpr int SLABS = NBLK / L1BLK;  // 64 slabs per reduce block
constexpr int L1BASE   = 1024;       // ws float offset of level-1 partials
constexpr int PARTBASE = 16384;      // ws float offset of per-block slabs

__device__ __forceinline__ short f2bf(float f) {
  return (short)__bfloat16_as_ushort(__float2bfloat16(f));
}

// ---- 4-deep pipelined one-hot MFMA over contiguous per-wave pixel chunks ----

#define LOADSET(PA, PB, LA, LB, K)                                             \
  {                                                                            \
    int kc_ = (K); if (kc_ > lastk) kc_ = lastk;                               \
    const size_t px_ = (size_t)kc_ * PXS + quad * 8;                           \
    if (isch) {                                                                \
      PA = *(const float4*)(predch + px_);                                     \
      PB = *(const float4*)(predch + px_ + 4);                                 \
    }                                                                          \
    LA = *(const int4*)(lab + px_);                                            \
    LB = *(const int4*)(lab + px_ + 4);                                        \
  }

#define COMPSET(PA, PB, LA, LB, K)                                             \
  if ((K) < kend) {                                                            \
    short8 A0_, A1_, B_;                                                       \
    A0_[0] = (LA.x == ms0) ? ONE : (short)0;                                   \
    A0_[1] = (LA.y == ms0) ? ONE : (short)0;                                   \
    A0_[2] = (LA.z == ms0) ? ONE : (short)0;                                   \
    A0_[3] = (LA.w == ms0) ? ONE : (short)0;                                   \
    A0_[4] = (LB.x == ms0) ? ONE : (short)0;                                   \
    A0_[5] = (LB.y == ms0) ? ONE : (short)0;                                   \
    A0_[6] = (LB.z == ms0) ? ONE : (short)0;                                   \
    A0_[7] = (LB.w == ms0) ? ONE : (short)0;                                   \
    A1_[0] = (LA.x == ms1) ? ONE : (short)0;                                   \
    A1_[1] = (LA.y == ms1) ? ONE : (short)0;                                   \
    A1_[2] = (LA.z == ms1) ? ONE : (short)0;                                   \
    A1_[3] = (LA.w == ms1) ? ONE : (short)0;                                   \
    A1_[4] = (LB.x == ms1) ? ONE : (short)0;                                   \
    A1_[5] = (LB.y == ms1) ? ONE : (short)0;                                   \
    A1_[6] = (LB.z == ms1) ? ONE : (short)0;                                   \
    A1_[7] = (LB.w == ms1) ? ONE : (short)0;                                   \
    if (isch) {                                                                \
      B_[0] = f2bf(PA.x); B_[1] = f2bf(PA.y);                                  \
      B_[2] = f2bf(PA.z); B_[3] = f2bf(PA.w);                                  \
      B_[4] = f2bf(PB.x); B_[5] = f2bf(PB.y);                                  \
      B_[6] = f2bf(PB.z); B_[7] = f2bf(PB.w);                                  \
    } else {                                                                   \
      B_ = Bconst;                                                             \
    }                                                                          \
    acc0 = __builtin_amdgcn_mfma_f32_16x16x32_bf16(A0_, B_, acc0, 0, 0, 0);    \
    acc1 = __builtin_amdgcn_mfma_f32_16x16x32_bf16(A1_, B_, acc1, 0, 0, 0);    \
  }

__global__ __launch_bounds__(BLK, 4)
void seg_mfma(const float* __restrict__ pred,
              const int*   __restrict__ lab,
              float*       __restrict__ ws,
              int P) {
  __shared__ float red[WPB][NROWS];
  const int tid  = threadIdx.x;
  const int wid  = tid >> 6;
  const int lane = tid & 63;
  const int colq = lane & 15;   // D col: 0..7 channel, 8 count, 9..15 unused
  const int quad = lane >> 4;   // k-group (8 px each)
  const int ms0  = colq + 1;    // acc0: segments 1..16
  const int ms1  = colq + 17;   // acc1: segments 17..32
  const short ONE = (short)0x3F80;

  const int nsteps = P / PXS;
  const int cpw    = (nsteps + NWAVE - 1) / NWAVE;   // contiguous steps per wave
  const int gw     = blockIdx.x * WPB + wid;
  const int k0     = gw * cpw;
  const int kend   = (k0 + cpw < nsteps) ? (k0 + cpw) : nsteps;
  const int lastk  = nsteps - 1;
  const bool isch  = (colq < 8);
  const float* predch = pred + (size_t)(colq & 7) * P;

  f32x4 acc0 = {0.f, 0.f, 0.f, 0.f};
  f32x4 acc1 = {0.f, 0.f, 0.f, 0.f};

  short8 Bconst;   // col 8 -> bf16 1.0 (counts); cols 9..15 -> 0
  {
    const short v = (colq == 8) ? ONE : (short)0;
#pragma unroll
    for (int i = 0; i < 8; ++i) Bconst[i] = v;
  }

  float4 pa0 = {}, pb0 = {}, pa1 = {}, pb1 = {};
  float4 pa2 = {}, pb2 = {}, pa3 = {}, pb3 = {};
  int4   la0, lb0, la1, lb1, la2, lb2, la3, lb3;

  LOADSET(pa0, pb0, la0, lb0, k0)
  LOADSET(pa1, pb1, la1, lb1, k0 + 1)
  LOADSET(pa2, pb2, la2, lb2, k0 + 2)
  LOADSET(pa3, pb3, la3, lb3, k0 + 3)

  for (int kk = k0; kk < k0 + cpw; kk += 4) {
    COMPSET(pa0, pb0, la0, lb0, kk)
    LOADSET(pa0, pb0, la0, lb0, kk + 4)
    COMPSET(pa1, pb1, la1, lb1, kk + 1)
    LOADSET(pa1, pb1, la1, lb1, kk + 5)
    COMPSET(pa2, pb2, la2, lb2, kk + 2)
    LOADSET(pa2, pb2, la2, lb2, kk + 6)
    COMPSET(pa3, pb3, la3, lb3, kk + 3)
    LOADSET(pa3, pb3, la3, lb3, kk + 7)
  }

  // D layout (m89/m91-verified): col = lane&15, row = (lane>>4)*4 + reg.
  // acc0 row r -> segment r+1 ; acc1 row r -> segment r+17.
  if (colq < RPS) {
#pragma unroll
    for (int r = 0; r < 4; ++r)
      red[wid][(quad * 4 + r) * RPS + colq] = acc0[r];
#pragma unroll
    for (int r = 0; r < 4; ++r)
      red[wid][(16 + quad * 4 + r) * RPS + colq] = acc1[r];
  }
  __syncthreads();
  for (int v = tid; v < NROWS; v += BLK) {
    float s = 0.f;
#pragma unroll
    for (int w = 0; w < WPB; ++w) s += red[w][v];
    ws[PARTBASE + (size_t)blockIdx.x * NROWS + v] = s;   // plain-store slab
  }
}

// Level-1: block b sums SLABS contiguous slabs (coalesced) -> plain store.
__global__ __launch_bounds__(256)
void reduce1(float* __restrict__ ws) {
  const int b = blockIdx.x;
  for (int v = threadIdx.x; v < NROWS; v += 256) {
    float s = 0.f;
#pragma unroll 4
    for (int i = 0; i < SLABS; ++i)
      s += ws[PARTBASE + (size_t)(b * SLABS + i) * NROWS + v];
    ws[L1BASE + (size_t)b * NROWS + v] = s;
  }
}

// Fallback (C != 8 or P % 32 != 0): LDS-atomic bins, plain-store slabs.
__global__ __launch_bounds__(BLK)
void seg_gen(const float* __restrict__ pred,
             const int*   __restrict__ lab,
             float*       __restrict__ ws,
             int P, int C) {
  __shared__ float bins[(NSEGF + 1) * RPS];
  const int tid = threadIdx.x;
  for (int i = tid; i < (NSEGF + 1) * RPS; i += BLK) bins[i] = 0.f;
  __syncthreads();
  const int stride = gridDim.x * BLK;
  const int Cc = C < 8 ? C : 8;
  for (int p = blockIdx.x * BLK + tid; p < P; p += stride) {
    int lb = lab[p]; if (lb < 0) lb = 0; if (lb > NSEGF) lb = NSEGF;
    const int o = lb * RPS;
    unsafeAtomicAdd(&bins[o + 8], 1.f);
    for (int c = 0; c < Cc; ++c)
      unsafeAtomicAdd(&bins[o + c], pred[(size_t)c * P + p]);
  }
  __syncthreads();
  for (int i = tid; i < NROWS; i += BLK)
    ws[PARTBASE + (size_t)blockIdx.x * NROWS + i] = bins[RPS + i];
}

__global__ __launch_bounds__(64)
void finish_kernel(const float* __restrict__ ws,
                   const int*   __restrict__ nkp,
                   float*       __restrict__ out,
                   int C) {
  __shared__ float sfin[NROWS];
  __shared__ float sA[NSEGF + 1];
  int K = *nkp; if (K > NSEGF) K = NSEGF;
  const int tid = threadIdx.x;
  const int Cc = C < 8 ? C : 8;

  for (int v = tid; v < NROWS; v += 64) {
    float s = 0.f;
#pragma unroll 4
    for (int b = 0; b < L1BLK; ++b) s += ws[L1BASE + (size_t)b * NROWS + v];
    sfin[v] = s;
  }
  for (int k = tid; k <= NSEGF; k += 64) sA[k] = 0.f;
  __syncthreads();
  for (int k = 1 + tid; k <= K; k += 64) {
    float s2 = 0.f;
    for (int c = 0; c < Cc; ++c) {
      const float v = sfin[(k - 1) * RPS + c];
      s2 = fmaf(v, v, s2);
    }
    sA[k] = sfin[(k - 1) * RPS + 8] * s2;
  }
  __syncthreads();

  // All-lane pair loop (R5 lesson: one-lane-at-a-time guard = 90us serial).
  const int npairs = K * (K - 1) / 2;
  float accv = 0.f;
  for (int idx = tid; idx < npairs; idx += 64) {
    int i = 1, rem = idx;
    while (rem >= K - i) { rem -= K - i; ++i; }
    const int j = i + 1 + rem;
    const float ps = sA[i] + sA[j];
    const float d  = fmaxf(3.0f - sqrtf(ps), 0.f);
    accv += logf(fmaf(d, d, 1.f));
  }
#pragma unroll
  for (int off = 32; off > 0; off >>= 1) accv += __shfl_down(accv, off);
  if (tid == 0) out[0] = accv * (float)(K - 1) / (float)K;
}

extern "C" void kernel_launch(void* const* d_in, const int* in_sizes, int n_in,
                              void* d_out, int out_size, void* d_ws, size_t ws_size,
                              hipStream_t stream) {
  const float* pred = (const float*)d_in[0];
  const int*   lab  = (const int*)d_in[2];
  const int*   nkp  = (const int*)d_in[3];
  float*       out  = (float*)d_out;
  float*       ws   = (float*)d_ws;

  const int P = in_sizes[2];        // H*W
  const int C = in_sizes[0] / P;    // channels

  const bool fast = (C == 8) && (P % PXS) == 0;

  if (fast) {
    seg_mfma<<<NBLK, BLK, 0, stream>>>(pred, lab, ws, P);
  } else {
    seg_gen<<<NBLK, BLK, 0, stream>>>(pred, lab, ws, P, C);
  }
  reduce1<<<L1BLK, 256, 0, stream>>>(ws);
  finish_kernel<<<1, 64, 0, stream>>>(ws, nkp, out, C);
}

// Round 9
// 59.415 us; speedup vs baseline: 1.1199x; 1.1199x over previous
//
#include <hip/hip_runtime.h>
#include <hip/hip_bf16.h>
#include <math.h>

// DiscriminationLoss via MFMA (R9):
//   S[k,c] = sum_{p: label[p]=k} pred[c,p],  N[k] = |{p: label[p]=k}|, k=1..32
//   A[k]   = N[k] * sum_c S[k,c]^2
//   L      = sum_{i<j} log(max(3 - sqrt(A_i + A_j), 0)^2 + 1);  out = L*(K-1)/K
//
// R8 lesson: VGPR_Count=40 proved the compiler collapsed the 4-deep register
// pipeline (loads sunk to just before use -> serial latency chain). R9 pins
// the schedule with asm memory fences between each COMP/LOAD pair: loads
// cannot sink past a fence, giving a true 4-deep issue->use distance plus
// 4 waves/SIMD TLP. Strided (frontier) step order; 1024 blocks co-resident.
// Zero LDS in the main loop, zero atomics, zero memset.

typedef __attribute__((ext_vector_type(8))) short short8;
typedef __attribute__((ext_vector_type(4))) float f32x4;

constexpr int NSEGF = 32;            // segments 1..32 (label 0 = background, dropped)
constexpr int RPS   = 9;             // 8 channels + count
constexpr int NROWS = NSEGF * RPS;   // 288
constexpr int BLK   = 256;
constexpr int WPB   = 4;
constexpr int NBLK  = 1024;          // 4 blocks/CU, exactly co-resident
constexpr int NWAVE = NBLK * WPB;    // 4096 waves
constexpr int PXS   = 32;            // pixels per k-step (K of 16x16x32)
constexpr int L1BLK = 32;            // level-1 reduce blocks
constexpr int SLABS = NBLK / L1BLK;  // 32 slabs per reduce block
constexpr int L1BASE   = 1024;       // ws float offset of level-1 partials
constexpr int PARTBASE = 16384;      // ws float offset of per-block slabs

#define SCHED_FENCE asm volatile("" ::: "memory")

__device__ __forceinline__ short f2bf(float f) {
  return (short)__bfloat16_as_ushort(__float2bfloat16(f));
}

// Load one k-step's operand data into named registers (clamped index).
#define LOADSET(PA, PB, LA, LB, KIDX)                                          \
  {                                                                            \
    int kc_ = (KIDX); if (kc_ > lastk) kc_ = lastk;                            \
    const size_t px_ = (size_t)kc_ * PXS + quad * 8;                           \
    if (isch) {                                                                \
      PA = *(const float4*)(predch + px_);                                     \
      PB = *(const float4*)(predch + px_ + 4);                                 \
    }                                                                          \
    LA = *(const int4*)(lab + px_);                                            \
    LB = *(const int4*)(lab + px_ + 4);                                        \
  }

#define COMPSET(PA, PB, LA, LB, KIDX)                                          \
  if ((KIDX) < nsteps) {                                                       \
    short8 A0_, A1_, B_;                                                       \
    A0_[0] = (LA.x == ms0) ? ONE : (short)0;                                   \
    A0_[1] = (LA.y == ms0) ? ONE : (short)0;                                   \
    A0_[2] = (LA.z == ms0) ? ONE : (short)0;                                   \
    A0_[3] = (LA.w == ms0) ? ONE : (short)0;                                   \
    A0_[4] = (LB.x == ms0) ? ONE : (short)0;                                   \
    A0_[5] = (LB.y == ms0) ? ONE : (short)0;                                   \
    A0_[6] = (LB.z == ms0) ? ONE : (short)0;                                   \
    A0_[7] = (LB.w == ms0) ? ONE : (short)0;                                   \
    A1_[0] = (LA.x == ms1) ? ONE : (short)0;                                   \
    A1_[1] = (LA.y == ms1) ? ONE : (short)0;                                   \
    A1_[2] = (LA.z == ms1) ? ONE : (short)0;                                   \
    A1_[3] = (LA.w == ms1) ? ONE : (short)0;                                   \
    A1_[4] = (LB.x == ms1) ? ONE : (short)0;                                   \
    A1_[5] = (LB.y == ms1) ? ONE : (short)0;                                   \
    A1_[6] = (LB.z == ms1) ? ONE : (short)0;                                   \
    A1_[7] = (LB.w == ms1) ? ONE : (short)0;                                   \
    if (isch) {                                                                \
      B_[0] = f2bf(PA.x); B_[1] = f2bf(PA.y);                                  \
      B_[2] = f2bf(PA.z); B_[3] = f2bf(PA.w);                                  \
      B_[4] = f2bf(PB.x); B_[5] = f2bf(PB.y);                                  \
      B_[6] = f2bf(PB.z); B_[7] = f2bf(PB.w);                                  \
    } else {                                                                   \
      B_ = Bconst;                                                             \
    }                                                                          \
    acc0 = __builtin_amdgcn_mfma_f32_16x16x32_bf16(A0_, B_, acc0, 0, 0, 0);    \
    acc1 = __builtin_amdgcn_mfma_f32_16x16x32_bf16(A1_, B_, acc1, 0, 0, 0);    \
  }

__global__ __launch_bounds__(BLK, 4)
void seg_mfma(const float* __restrict__ pred,
              const int*   __restrict__ lab,
              float*       __restrict__ ws,
              int P) {
  __shared__ float red[WPB][NROWS];
  const int tid  = threadIdx.x;
  const int wid  = tid >> 6;
  const int lane = tid & 63;
  const int colq = lane & 15;   // D col: 0..7 channel, 8 count, 9..15 unused
  const int quad = lane >> 4;   // k-group (8 px each)
  const int ms0  = colq + 1;    // acc0: segments 1..16
  const int ms1  = colq + 17;   // acc1: segments 17..32
  const short ONE = (short)0x3F80;

  const int nsteps = P / PXS;
  const int lastk  = nsteps - 1;
  const int gw     = blockIdx.x * WPB + wid;
  const int spw    = (nsteps + NWAVE - 1) / NWAVE;   // steps per wave (strided)
  const bool isch  = (colq < 8);
  const float* predch = pred + (size_t)(colq & 7) * P;

  f32x4 acc0 = {0.f, 0.f, 0.f, 0.f};
  f32x4 acc1 = {0.f, 0.f, 0.f, 0.f};

  short8 Bconst;   // col 8 -> bf16 1.0 (counts); cols 9..15 -> 0
  {
    const short v = (colq == 8) ? ONE : (short)0;
#pragma unroll
    for (int i = 0; i < 8; ++i) Bconst[i] = v;
  }

  float4 pa0 = {}, pb0 = {}, pa1 = {}, pb1 = {};
  float4 pa2 = {}, pb2 = {}, pa3 = {}, pb3 = {};
  int4   la0, lb0, la1, lb1, la2, lb2, la3, lb3;

  int k = gw;
  LOADSET(pa0, pb0, la0, lb0, k)
  LOADSET(pa1, pb1, la1, lb1, k + NWAVE)
  LOADSET(pa2, pb2, la2, lb2, k + 2 * NWAVE)
  LOADSET(pa3, pb3, la3, lb3, k + 3 * NWAVE)

  for (int i = 0; i < spw; i += 4) {
    SCHED_FENCE;
    COMPSET(pa0, pb0, la0, lb0, k)
    LOADSET(pa0, pb0, la0, lb0, k + 4 * NWAVE)
    SCHED_FENCE;
    COMPSET(pa1, pb1, la1, lb1, k + NWAVE)
    LOADSET(pa1, pb1, la1, lb1, k + 5 * NWAVE)
    SCHED_FENCE;
    COMPSET(pa2, pb2, la2, lb2, k + 2 * NWAVE)
    LOADSET(pa2, pb2, la2, lb2, k + 6 * NWAVE)
    SCHED_FENCE;
    COMPSET(pa3, pb3, la3, lb3, k + 3 * NWAVE)
    LOADSET(pa3, pb3, la3, lb3, k + 7 * NWAVE)
    k += 4 * NWAVE;
  }

  // D layout (m89/m91-verified): col = lane&15, row = (lane>>4)*4 + reg.
  // acc0 row r -> segment r+1 ; acc1 row r -> segment r+17.
  if (colq < RPS) {
#pragma unroll
    for (int r = 0; r < 4; ++r)
      red[wid][(quad * 4 + r) * RPS + colq] = acc0[r];
#pragma unroll
    for (int r = 0; r < 4; ++r)
      red[wid][(16 + quad * 4 + r) * RPS + colq] = acc1[r];
  }
  __syncthreads();
  for (int v = tid; v < NROWS; v += BLK) {
    float s = 0.f;
#pragma unroll
    for (int w = 0; w < WPB; ++w) s += red[w][v];
    ws[PARTBASE + (size_t)blockIdx.x * NROWS + v] = s;   // plain-store slab
  }
}

// Level-1: block b sums SLABS slabs; reads are coalesced across threads
// (v contiguous per inner iteration). Plain store to L1BASE.
__global__ __launch_bounds__(256)
void reduce1(float* __restrict__ ws) {
  const int b = blockIdx.x;
  for (int v = threadIdx.x; v < NROWS; v += 256) {
    float s = 0.f;
#pragma unroll 4
    for (int i = 0; i < SLABS; ++i)
      s += ws[PARTBASE + (size_t)(b * SLABS + i) * NROWS + v];
    ws[L1BASE + (size_t)b * NROWS + v] = s;
  }
}

// Fallback (C != 8 or P % 32 != 0): LDS-atomic bins, plain-store slabs.
__global__ __launch_bounds__(BLK)
void seg_gen(const float* __restrict__ pred,
             const int*   __restrict__ lab,
             float*       __restrict__ ws,
             int P, int C) {
  __shared__ float bins[(NSEGF + 1) * RPS];
  const int tid = threadIdx.x;
  for (int i = tid; i < (NSEGF + 1) * RPS; i += BLK) bins[i] = 0.f;
  __syncthreads();
  const int stride = gridDim.x * BLK;
  const int Cc = C < 8 ? C : 8;
  for (int p = blockIdx.x * BLK + tid; p < P; p += stride) {
    int lb = lab[p]; if (lb < 0) lb = 0; if (lb > NSEGF) lb = NSEGF;
    const int o = lb * RPS;
    unsafeAtomicAdd(&bins[o + 8], 1.f);
    for (int c = 0; c < Cc; ++c)
      unsafeAtomicAdd(&bins[o + c], pred[(size_t)c * P + p]);
  }
  __syncthreads();
  for (int i = tid; i < NROWS; i += BLK)
    ws[PARTBASE + (size_t)blockIdx.x * NROWS + i] = bins[RPS + i];
}

__global__ __launch_bounds__(64)
void finish_kernel(const float* __restrict__ ws,
                   const int*   __restrict__ nkp,
                   float*       __restrict__ out,
                   int C) {
  __shared__ float sfin[NROWS];
  __shared__ float sA[NSEGF + 1];
  int K = *nkp; if (K > NSEGF) K = NSEGF;
  const int tid = threadIdx.x;
  const int Cc = C < 8 ? C : 8;

  for (int v = tid; v < NROWS; v += 64) {
    float s = 0.f;
#pragma unroll 4
    for (int b = 0; b < L1BLK; ++b) s += ws[L1BASE + (size_t)b * NROWS + v];
    sfin[v] = s;
  }
  for (int k = tid; k <= NSEGF; k += 64) sA[k] = 0.f;
  __syncthreads();
  for (int k = 1 + tid; k <= K; k += 64) {
    float s2 = 0.f;
    for (int c = 0; c < Cc; ++c) {
      const float v = sfin[(k - 1) * RPS + c];
      s2 = fmaf(v, v, s2);
    }
    sA[k] = sfin[(k - 1) * RPS + 8] * s2;
  }
  __syncthreads();

  // All-lane pair loop (R5 lesson: one-lane-at-a-time guard = 90us serial).
  const int npairs = K * (K - 1) / 2;
  float accv = 0.f;
  for (int idx = tid; idx < npairs; idx += 64) {
    int i = 1, rem = idx;
    while (rem >= K - i) { rem -= K - i; ++i; }
    const int j = i + 1 + rem;
    const float ps = sA[i] + sA[j];
    const float d  = fmaxf(3.0f - sqrtf(ps), 0.f);
    accv += logf(fmaf(d, d, 1.f));
  }
#pragma unroll
  for (int off = 32; off > 0; off >>= 1) accv += __shfl_down(accv, off);
  if (tid == 0) out[0] = accv * (float)(K - 1) / (float)K;
}

extern "C" void kernel_launch(void* const* d_in, const int* in_sizes, int n_in,
                              void* d_out, int out_size, void* d_ws, size_t ws_size,
                              hipStream_t stream) {
  const float* pred = (const float*)d_in[0];
  const int*   lab  = (const int*)d_in[2];
  const int*   nkp  = (const int*)d_in[3];
  float*       out  = (float*)d_out;
  float*       ws   = (float*)d_ws;

  const int P = in_sizes[2];        // H*W
  const int C = in_sizes[0] / P;    // channels

  const bool fast = (C == 8) && (P % PXS) == 0;

  if (fast) {
    seg_mfma<<<NBLK, BLK, 0, stream>>>(pred, lab, ws, P);
  } else {
    seg_gen<<<NBLK, BLK, 0, stream>>>(pred, lab, ws, P, C);
  }
  reduce1<<<L1BLK, 256, 0, stream>>>(ws);
  finish_kernel<<<1, 64, 0, stream>>>(ws, nkp, out, C);
}

// Round 10
// 45.709 us; speedup vs baseline: 1.4557x; 1.2999x over previous
//
#include <hip/hip_runtime.h>
#include <hip/hip_bf16.h>
#include <math.h>

// DiscriminationLoss via MFMA (R10):
//   S[k,c] = sum_{p: label[p]=k} pred[c,p],  N[k] = |{p: label[p]=k}|, k=1..32
//   A[k]   = N[k] * sum_c S[k,c]^2
//   L      = sum_{i<j} log(max(3 - sqrt(A_i + A_j), 0)^2 + 1);  out = L*(K-1)/K
//
// R9 lessons: totals invariant (~57) across 3 seg structures => large non-seg
// constant: strided finish reads (1 wave x 1152B-stride), reduce layout, node
// overhead. R10: (1) seg: contiguous per-wave spans + XCD-bijective swizzle +
// scalar step index (SGPR-base addressing), fenced 4-deep pipeline kept;
// (2) reduce1 writes level-1 partials transposed [row][block]; (3) finish =
// 256 threads, coalesced 128B row reads. Zero atomics, zero memset.

typedef __attribute__((ext_vector_type(8))) short short8;
typedef __attribute__((ext_vector_type(4))) float f32x4;

constexpr int NSEGF = 32;            // segments 1..32 (label 0 = background, dropped)
constexpr int RPS   = 9;             // 8 channels + count
constexpr int NROWS = NSEGF * RPS;   // 288
constexpr int BLK   = 256;
constexpr int WPB   = 4;
constexpr int NBLK  = 1024;          // 4 blocks/CU, exactly co-resident
constexpr int NWAVE = NBLK * WPB;    // 4096 waves
constexpr int PXS   = 32;            // pixels per k-step (K of 16x16x32)
constexpr int L1BLK = 32;            // level-1 reduce blocks
constexpr int SLABS = NBLK / L1BLK;  // 32 slabs per reduce block
constexpr int L1BASE   = 1024;       // ws float offset of level-1 partials [row][block]
constexpr int PARTBASE = 16384;      // ws float offset of per-block slabs [block][row]

#define SCHED_FENCE asm volatile("" ::: "memory")

__device__ __forceinline__ short f2bf(float f) {
  return (short)__bfloat16_as_ushort(__float2bfloat16(f));
}

__device__ __forceinline__ float wave_sum64(float x) {
  int t;
  t = __builtin_amdgcn_update_dpp(0, __float_as_int(x), 0x111, 0xf, 0xf, true); x += __int_as_float(t);
  t = __builtin_amdgcn_update_dpp(0, __float_as_int(x), 0x112, 0xf, 0xf, true); x += __int_as_float(t);
  t = __builtin_amdgcn_update_dpp(0, __float_as_int(x), 0x114, 0xf, 0xf, true); x += __int_as_float(t);
  t = __builtin_amdgcn_update_dpp(0, __float_as_int(x), 0x118, 0xf, 0xf, true); x += __int_as_float(t);
  t = __builtin_amdgcn_update_dpp(0, __float_as_int(x), 0x142, 0xf, 0xf, true); x += __int_as_float(t);
  t = __builtin_amdgcn_update_dpp(0, __float_as_int(x), 0x143, 0xf, 0xf, true); x += __int_as_float(t);
  return x;  // lane 63 holds the sum
}

// Load one k-step's operands into named registers. KIDX is wave-uniform
// (scalar); only the dead prefetch tail is clamped.
#define LOADSET(PA, PB, LA, LB, KIDX)                                          \
  {                                                                            \
    int kc_ = (KIDX); if (kc_ > lastk) kc_ = lastk;                            \
    const size_t off_ = (size_t)kc_ * PXS;                                     \
    if (isch) {                                                                \
      PA = *(const float4*)(pc + off_);                                        \
      PB = *(const float4*)(pc + off_ + 4);                                    \
    }                                                                          \
    LA = *(const int4*)(lp + off_);                                            \
    LB = *(const int4*)(lp + off_ + 4);                                        \
  }

#define COMPSET(PA, PB, LA, LB)                                                \
  {                                                                            \
    short8 A0_, A1_, B_;                                                       \
    A0_[0] = (LA.x == ms0) ? ONE : (short)0;                                   \
    A0_[1] = (LA.y == ms0) ? ONE : (short)0;                                   \
    A0_[2] = (LA.z == ms0) ? ONE : (short)0;                                   \
    A0_[3] = (LA.w == ms0) ? ONE : (short)0;                                   \
    A0_[4] = (LB.x == ms0) ? ONE : (short)0;                                   \
    A0_[5] = (LB.y == ms0) ? ONE : (short)0;                                   \
    A0_[6] = (LB.z == ms0) ? ONE : (short)0;                                   \
    A0_[7] = (LB.w == ms0) ? ONE : (short)0;                                   \
    A1_[0] = (LA.x == ms1) ? ONE : (short)0;                                   \
    A1_[1] = (LA.y == ms1) ? ONE : (short)0;                                   \
    A1_[2] = (LA.z == ms1) ? ONE : (short)0;                                   \
    A1_[3] = (LA.w == ms1) ? ONE : (short)0;                                   \
    A1_[4] = (LB.x == ms1) ? ONE : (short)0;                                   \
    A1_[5] = (LB.y == ms1) ? ONE : (short)0;                                   \
    A1_[6] = (LB.z == ms1) ? ONE : (short)0;                                   \
    A1_[7] = (LB.w == ms1) ? ONE : (short)0;                                   \
    if (isch) {                                                                \
      B_[0] = f2bf(PA.x); B_[1] = f2bf(PA.y);                                  \
      B_[2] = f2bf(PA.z); B_[3] = f2bf(PA.w);                                  \
      B_[4] = f2bf(PB.x); B_[5] = f2bf(PB.y);                                  \
      B_[6] = f2bf(PB.z); B_[7] = f2bf(PB.w);                                  \
    } else {                                                                   \
      B_ = Bconst;                                                             \
    }                                                                          \
    acc0 = __builtin_amdgcn_mfma_f32_16x16x32_bf16(A0_, B_, acc0, 0, 0, 0);    \
    acc1 = __builtin_amdgcn_mfma_f32_16x16x32_bf16(A1_, B_, acc1, 0, 0, 0);    \
  }

__global__ __launch_bounds__(BLK, 4)
void seg_mfma(const float* __restrict__ pred,
              const int*   __restrict__ lab,
              float*       __restrict__ ws,
              int P) {
  __shared__ float red[WPB][NROWS];
  const int tid  = threadIdx.x;
  const int wid  = tid >> 6;
  const int lane = tid & 63;
  const int colq = lane & 15;   // D col: 0..7 channel, 8 count, 9..15 unused
  const int quad = lane >> 4;   // k-group (8 px each)
  const int ms0  = colq + 1;    // acc0: segments 1..16
  const int ms1  = colq + 17;   // acc1: segments 17..32
  const short ONE = (short)0x3F80;

  // XCD-bijective block swizzle: XCD x owns a contiguous 1/8 of the data.
  const int bs = (blockIdx.x & 7) * (NBLK / 8) + (blockIdx.x >> 3);
  const int gw = bs * WPB + wid;

  const int nsteps = P / PXS;
  const int spw    = nsteps / NWAVE;     // contiguous steps per wave (guarded %4==0)
  const int kbase  = gw * spw;
  const int lastk  = nsteps - 1;
  const bool isch  = (colq < 8);
  const float* pc = pred + (size_t)(colq & 7) * P + quad * 8;
  const int*   lp = lab + quad * 8;

  f32x4 acc0 = {0.f, 0.f, 0.f, 0.f};
  f32x4 acc1 = {0.f, 0.f, 0.f, 0.f};

  short8 Bconst;   // col 8 -> bf16 1.0 (counts); cols 9..15 -> 0
  {
    const short v = (colq == 8) ? ONE : (short)0;
#pragma unroll
    for (int i = 0; i < 8; ++i) Bconst[i] = v;
  }

  float4 pa0 = {}, pb0 = {}, pa1 = {}, pb1 = {};
  float4 pa2 = {}, pb2 = {}, pa3 = {}, pb3 = {};
  int4   la0, lb0, la1, lb1, la2, lb2, la3, lb3;

  int k = kbase;
  LOADSET(pa0, pb0, la0, lb0, k)
  LOADSET(pa1, pb1, la1, lb1, k + 1)
  LOADSET(pa2, pb2, la2, lb2, k + 2)
  LOADSET(pa3, pb3, la3, lb3, k + 3)

  for (int i = 0; i < spw; i += 4) {
    SCHED_FENCE;
    COMPSET(pa0, pb0, la0, lb0)
    LOADSET(pa0, pb0, la0, lb0, k + 4)
    SCHED_FENCE;
    COMPSET(pa1, pb1, la1, lb1)
    LOADSET(pa1, pb1, la1, lb1, k + 5)
    SCHED_FENCE;
    COMPSET(pa2, pb2, la2, lb2)
    LOADSET(pa2, pb2, la2, lb2, k + 6)
    SCHED_FENCE;
    COMPSET(pa3, pb3, la3, lb3)
    LOADSET(pa3, pb3, la3, lb3, k + 7)
    k += 4;
  }

  // D layout (m89/m91-verified): col = lane&15, row = (lane>>4)*4 + reg.
  // acc0 row r -> segment r+1 ; acc1 row r -> segment r+17.
  if (colq < RPS) {
#pragma unroll
    for (int r = 0; r < 4; ++r)
      red[wid][(quad * 4 + r) * RPS + colq] = acc0[r];
#pragma unroll
    for (int r = 0; r < 4; ++r)
      red[wid][(16 + quad * 4 + r) * RPS + colq] = acc1[r];
  }
  __syncthreads();
  for (int v = tid; v < NROWS; v += BLK) {
    float s = 0.f;
#pragma unroll
    for (int w = 0; w < WPB; ++w) s += red[w][v];
    ws[PARTBASE + (size_t)blockIdx.x * NROWS + v] = s;   // plain-store slab
  }
}

// Level-1: block b sums SLABS contiguous slabs (coalesced reads); writes
// TRANSPOSED [row][block] so finish reads 128B-contiguous rows.
__global__ __launch_bounds__(256)
void reduce1(float* __restrict__ ws) {
  const int b = blockIdx.x;
  for (int v = threadIdx.x; v < NROWS; v += 256) {
    float s = 0.f;
#pragma unroll 4
    for (int i = 0; i < SLABS; ++i)
      s += ws[PARTBASE + (size_t)(b * SLABS + i) * NROWS + v];
    ws[L1BASE + (size_t)v * L1BLK + b] = s;
  }
}

// Fallback (C != 8 or bad divisibility): LDS-atomic bins, plain-store slabs.
__global__ __launch_bounds__(BLK)
void seg_gen(const float* __restrict__ pred,
             const int*   __restrict__ lab,
             float*       __restrict__ ws,
             int P, int C) {
  __shared__ float bins[(NSEGF + 1) * RPS];
  const int tid = threadIdx.x;
  for (int i = tid; i < (NSEGF + 1) * RPS; i += BLK) bins[i] = 0.f;
  __syncthreads();
  const int stride = gridDim.x * BLK;
  const int Cc = C < 8 ? C : 8;
  for (int p = blockIdx.x * BLK + tid; p < P; p += stride) {
    int lb = lab[p]; if (lb < 0) lb = 0; if (lb > NSEGF) lb = NSEGF;
    const int o = lb * RPS;
    unsafeAtomicAdd(&bins[o + 8], 1.f);
    for (int c = 0; c < Cc; ++c)
      unsafeAtomicAdd(&bins[o + c], pred[(size_t)c * P + p]);
  }
  __syncthreads();
  for (int i = tid; i < NROWS; i += BLK)
    ws[PARTBASE + (size_t)blockIdx.x * NROWS + i] = bins[RPS + i];
}

__global__ __launch_bounds__(256)
void finish_kernel(const float* __restrict__ ws,
                   const int*   __restrict__ nkp,
                   float*       __restrict__ out,
                   int C) {
  __shared__ float sfin[NROWS];
  __shared__ float sA[NSEGF + 1];
  __shared__ float wsum[4];
  int K = *nkp; if (K > NSEGF) K = NSEGF;
  const int tid = threadIdx.x;
  const int Cc = C < 8 ? C : 8;

  // Level-2 reduce: row v's 32 partials are contiguous (128B) -> coalesced.
  for (int v = tid; v < NROWS; v += 256) {
    const float* r = ws + L1BASE + (size_t)v * L1BLK;
    float s = 0.f;
#pragma unroll
    for (int b = 0; b < L1BLK; ++b) s += r[b];
    sfin[v] = s;
  }
  __syncthreads();
  for (int k = 1 + tid; k <= K; k += 256) {
    float s2 = 0.f;
    for (int c = 0; c < Cc; ++c) {
      const float v = sfin[(k - 1) * RPS + c];
      s2 = fmaf(v, v, s2);
    }
    sA[k] = sfin[(k - 1) * RPS + 8] * s2;
  }
  __syncthreads();

  // All-lane pair loop across 256 threads (~2 pairs/thread).
  const int npairs = K * (K - 1) / 2;
  float accv = 0.f;
  for (int idx = tid; idx < npairs; idx += 256) {
    int i = 1, rem = idx;
    while (rem >= K - i) { rem -= K - i; ++i; }
    const int j = i + 1 + rem;
    const float ps = sA[i] + sA[j];
    const float d  = fmaxf(3.0f - sqrtf(ps), 0.f);
    accv += logf(fmaf(d, d, 1.f));
  }
  accv = wave_sum64(accv);
  if ((tid & 63) == 63) wsum[tid >> 6] = accv;
  __syncthreads();
  if (tid == 0)
    out[0] = (wsum[0] + wsum[1] + wsum[2] + wsum[3]) * (float)(K - 1) / (float)K;
}

extern "C" void kernel_launch(void* const* d_in, const int* in_sizes, int n_in,
                              void* d_out, int out_size, void* d_ws, size_t ws_size,
                              hipStream_t stream) {
  const float* pred = (const float*)d_in[0];
  const int*   lab  = (const int*)d_in[2];
  const int*   nkp  = (const int*)d_in[3];
  float*       out  = (float*)d_out;
  float*       ws   = (float*)d_ws;

  const int P = in_sizes[2];        // H*W
  const int C = in_sizes[0] / P;    // channels

  const size_t need = (size_t)(PARTBASE + (size_t)NBLK * NROWS) * sizeof(float);
  const int spw = (P / PXS) / NWAVE;
  const bool fast = (C == 8) && (P % (PXS * NWAVE)) == 0 &&
                    spw >= 4 && (spw & 3) == 0 && ws_size >= need;

  if (fast) {
    seg_mfma<<<NBLK, BLK, 0, stream>>>(pred, lab, ws, P);
  } else {
    seg_gen<<<NBLK, BLK, 0, stream>>>(pred, lab, ws, P, C);
  }
  reduce1<<<L1BLK, 256, 0, stream>>>(ws);
  finish_kernel<<<1, 256, 0, stream>>>(ws, nkp, out, C);
}